// Round 1
// 220.428 us; speedup vs baseline: 1.0544x; 1.0544x over previous
//
#include <hip/hip_runtime.h>

// Causal FIR conv via FFT (n_fft = 131072), four-step N = 512 x 256,
// transpose-free, batch-packed (2 real rows -> 1 complex row).
// v6: mid_rows + fwd_rows_g rewritten as 16x16 four-step with FFT-16 fully
// in registers. Row exchange is intra-wave (16 threads/row in one wave):
// no __syncthreads in steady state (one barrier for the W256 table init),
// pitch-18 LDS layout = conflict-minimum b64/b128 access, constant-twiddle
// FFT-16 (specialized +-i, +-r2 multiplies), W256^{bc} from a shared table.

#define N_FFT 131072
#define N1    512
#define N2    256
#define T_LEN 65536
#define CB    128
#define PI_F  3.14159265358979323846f
#define R2_F  0.70710678118654752f
#define C16F  0.92387953251128675613f   // cos(pi/8)
#define S16F  0.38268343236508977173f   // sin(pi/8)

typedef __attribute__((ext_vector_type(2))) __fp16 h2;
typedef __attribute__((ext_vector_type(4))) __fp16 h4;
typedef __attribute__((ext_vector_type(8))) __fp16 h8;

__device__ inline int brev9(int x) { return (int)(__brev((unsigned)x) >> 23); }

__device__ inline float2 cadd(float2 a, float2 b){ return make_float2(a.x+b.x, a.y+b.y); }
__device__ inline float2 csub(float2 a, float2 b){ return make_float2(a.x-b.x, a.y-b.y); }
__device__ inline float2 cmul(float2 a, float2 b){ return make_float2(a.x*b.x-a.y*b.y, a.x*b.y+a.y*b.x); }
// a * conj(b)
__device__ inline float2 cmulc(float2 a, float2 b){ return make_float2(a.x*b.x+a.y*b.y, a.y*b.x-a.x*b.y); }
__device__ inline float2 csq(float2 a){ return make_float2(a.x*a.x-a.y*a.y, 2.f*a.x*a.y); }
__device__ inline float2 conjf(float2 a){ return make_float2(a.x, -a.y); }
__device__ inline float2 expif(float a){ float s,c; __sincosf(a,&s,&c); return make_float2(c,s); }
__device__ inline h2 f2h(float2 v){ return __builtin_amdgcn_cvt_pkrtz(v.x, v.y); }

// specialized constant complex multiplies
__device__ inline float2 mul_mi(float2 a){ return make_float2(a.y, -a.x); }                         // * (-i)
__device__ inline float2 mul_pi(float2 a){ return make_float2(-a.y, a.x); }                         // * (+i)
__device__ inline float2 mul_w81(float2 a){ return make_float2(R2_F*(a.x+a.y), R2_F*(a.y-a.x)); }   // * ( r2,-r2)
__device__ inline float2 mul_w83(float2 a){ return make_float2(R2_F*(a.y-a.x), -R2_F*(a.x+a.y)); }  // * (-r2,-r2)
__device__ inline float2 mul_w81c(float2 a){ return make_float2(R2_F*(a.x-a.y), R2_F*(a.x+a.y)); }  // * ( r2, r2)
__device__ inline float2 mul_w83c(float2 a){ return make_float2(-R2_F*(a.x+a.y), R2_F*(a.x-a.y)); } // * (-r2, r2)

// Fused DIF double stage (h then h/2). quad (p0, p0+h/2, p0+h, p0+3h/2)
__device__ inline void dif4(float2&a0, float2&a1, float2&a2, float2&a3, float2 w1, float2 w2){
    float2 s02 = cadd(a0,a2), d02 = csub(a0,a2);
    float2 s13 = cadd(a1,a3), d13 = csub(a1,a3);
    float2 b2 = cmul(w1,d02);
    float2 t  = cmul(w1,d13);
    float2 b3 = make_float2(t.y, -t.x);          // -i*t
    a0 = cadd(s02,s13);
    a1 = cmul(w2, csub(s02,s13));
    a2 = cadd(b2,b3);
    a3 = cmul(w2, csub(b2,b3));
}

// Fused DIT double stage (h then 2h), inverse twiddles. quad (p0, p0+h, p0+2h, p0+3h)
__device__ inline void dit4i(float2&a0, float2&a1, float2&a2, float2&a3, float2 w1, float2 w2){
    float2 t1 = cmul(w1,a1), t3 = cmul(w1,a3);
    float2 u0 = cadd(a0,t1), u1 = csub(a0,t1);
    float2 u2 = cadd(a2,t3), u3 = csub(a2,t3);
    float2 s2 = cmul(w2,u2), s3 = cmul(w2,u3);
    a0 = cadd(u0,s2); a2 = csub(u0,s2);
    a1 = make_float2(u1.x - s3.y, u1.y + s3.x);  // u1 + i*s3
    a3 = make_float2(u1.x + s3.y, u1.y - s3.x);  // u1 - i*s3
}

// 4-bit bit-reversal (involution)
__device__ constexpr int BR[16] = {0,8,4,12,2,10,6,14,1,9,5,13,3,11,7,15};

// ---------------------------------------------------------------------------
// FFT-16 fully in registers, forward DIF: natural input, output v[p]=X[BR[p]].
// All twiddles compile-time: W16^{1,3} full cmul; W8^{1,3}, +-i specialized.
// ---------------------------------------------------------------------------
__device__ __forceinline__ void fft16_fwd(float2 v[16]){
    // stage pair (8,4): quads (j, j+4, j+8, j+12), w1 = W16^j, w2 = W8^j
    { // j = 0 (trivial)
        float2 s02=cadd(v[0],v[8]),  d02=csub(v[0],v[8]);
        float2 s13=cadd(v[4],v[12]), d13=csub(v[4],v[12]);
        float2 b3 = mul_mi(d13);
        v[0]=cadd(s02,s13); v[4]=csub(s02,s13);
        v[8]=cadd(d02,b3);  v[12]=csub(d02,b3);
    }
    { // j = 1: w1=(C,-S), w2=W8^1
        float2 s02=cadd(v[1],v[9]),  d02=csub(v[1],v[9]);
        float2 s13=cadd(v[5],v[13]), d13=csub(v[5],v[13]);
        const float2 w1 = make_float2(C16F,-S16F);
        float2 b2 = cmul(w1,d02), b3 = mul_mi(cmul(w1,d13));
        v[1]=cadd(s02,s13);  v[5]=mul_w81(csub(s02,s13));
        v[9]=cadd(b2,b3);    v[13]=mul_w81(csub(b2,b3));
    }
    { // j = 2: w1=W8^1, w2=-i
        float2 s02=cadd(v[2],v[10]), d02=csub(v[2],v[10]);
        float2 s13=cadd(v[6],v[14]), d13=csub(v[6],v[14]);
        float2 b2 = mul_w81(d02), b3 = mul_mi(mul_w81(d13));
        v[2]=cadd(s02,s13);  v[6]=mul_mi(csub(s02,s13));
        v[10]=cadd(b2,b3);   v[14]=mul_mi(csub(b2,b3));
    }
    { // j = 3: w1=(S,-C), w2=W8^3
        float2 s02=cadd(v[3],v[11]), d02=csub(v[3],v[11]);
        float2 s13=cadd(v[7],v[15]), d13=csub(v[7],v[15]);
        const float2 w1 = make_float2(S16F,-C16F);
        float2 b2 = cmul(w1,d02), b3 = mul_mi(cmul(w1,d13));
        v[3]=cadd(s02,s13);  v[7]=mul_w83(csub(s02,s13));
        v[11]=cadd(b2,b3);   v[15]=mul_w83(csub(b2,b3));
    }
    // stage pair (2,1): contiguous quads, all trivial
#pragma unroll
    for (int q=0;q<4;q++){
        float2 a0=v[4*q],a1=v[4*q+1],a2=v[4*q+2],a3=v[4*q+3];
        float2 s02=cadd(a0,a2), d02=csub(a0,a2);
        float2 s13=cadd(a1,a3), d13=csub(a1,a3);
        float2 b3 = mul_mi(d13);
        v[4*q]=cadd(s02,s13);   v[4*q+1]=csub(s02,s13);
        v[4*q+2]=cadd(d02,b3);  v[4*q+3]=csub(d02,b3);
    }
}

// ---------------------------------------------------------------------------
// Inverse FFT-16 in registers (unnormalized, x16): input v[p]=F[BR[p]],
// natural-order output v[n] = sum_d W16^{-nd} F[d].
// ---------------------------------------------------------------------------
__device__ __forceinline__ void fft16_inv(float2 v[16]){
    // stage pair (1,2): contiguous quads, trivial
#pragma unroll
    for (int q=0;q<4;q++){
        float2 a0=v[4*q],a1=v[4*q+1],a2=v[4*q+2],a3=v[4*q+3];
        float2 u0=cadd(a0,a1), u1=csub(a0,a1);
        float2 u2=cadd(a2,a3), u3=csub(a2,a3);
        v[4*q]=cadd(u0,u2);   v[4*q+2]=csub(u0,u2);
        v[4*q+1]=make_float2(u1.x-u3.y, u1.y+u3.x);
        v[4*q+3]=make_float2(u1.x+u3.y, u1.y-u3.x);
    }
    // stage pair (4,8): quads (j, j+4, j+8, j+12), w1=conj(W8^j), w2=conj(W16^j)
    { // j = 0
        float2 t1=v[4], t3=v[12];
        float2 u0=cadd(v[0],t1), u1=csub(v[0],t1);
        float2 u2=cadd(v[8],t3), u3=csub(v[8],t3);
        v[0]=cadd(u0,u2); v[8]=csub(u0,u2);
        v[4]=make_float2(u1.x-u3.y, u1.y+u3.x);
        v[12]=make_float2(u1.x+u3.y, u1.y-u3.x);
    }
    { // j = 1: w1=(r2,r2), w2=(C,S)
        float2 t1=mul_w81c(v[5]), t3=mul_w81c(v[13]);
        float2 u0=cadd(v[1],t1), u1=csub(v[1],t1);
        float2 u2=cadd(v[9],t3), u3=csub(v[9],t3);
        const float2 w2 = make_float2(C16F,S16F);
        float2 s2=cmul(w2,u2), s3=cmul(w2,u3);
        v[1]=cadd(u0,s2); v[9]=csub(u0,s2);
        v[5]=make_float2(u1.x-s3.y, u1.y+s3.x);
        v[13]=make_float2(u1.x+s3.y, u1.y-s3.x);
    }
    { // j = 2: w1=+i, w2=(r2,r2)
        float2 t1=mul_pi(v[6]), t3=mul_pi(v[14]);
        float2 u0=cadd(v[2],t1), u1=csub(v[2],t1);
        float2 u2=cadd(v[10],t3), u3=csub(v[10],t3);
        float2 s2=mul_w81c(u2), s3=mul_w81c(u3);
        v[2]=cadd(u0,s2); v[10]=csub(u0,s2);
        v[6]=make_float2(u1.x-s3.y, u1.y+s3.x);
        v[14]=make_float2(u1.x+s3.y, u1.y-s3.x);
    }
    { // j = 3: w1=(-r2,r2), w2=(S,C)
        float2 t1=mul_w83c(v[7]), t3=mul_w83c(v[15]);
        float2 u0=cadd(v[3],t1), u1=csub(v[3],t1);
        float2 u2=cadd(v[11],t3), u3=csub(v[11],t3);
        const float2 w2 = make_float2(S16F,C16F);
        float2 s2=cmul(w2,u2), s3=cmul(w2,u3);
        v[3]=cadd(u0,s2); v[11]=csub(u0,s2);
        v[7]=make_float2(u1.x-s3.y, u1.y+s3.x);
        v[15]=make_float2(u1.x+s3.y, u1.y-s3.x);
    }
}

// ---------------------------------------------------------------------------
// Forward column FFT (512-pt DIF) over n1, 16 columns/block, + big twiddle,
// store at natural k1 = brev9(p). Upper half (n1>=256) implicit zero.
// ---------------------------------------------------------------------------
template<bool HALF>
__global__ __launch_bounds__(512, 4) void fwd_cols(
    const float* __restrict__ re_base, const float* __restrict__ im_base,
    long long row_stride, void* __restrict__ dstv)
{
    __shared__ float2 s[N1 * 16];                 // 64 KB
    const int tile = blockIdx.x, row = blockIdx.y, tid = threadIdx.x;
    const int n2base = tile * 16;
    const float* rp = re_base + (long long)row * row_stride;
    const float* ip = im_base ? (im_base + (long long)row * row_stride) : nullptr;

    {
        const int cp = tid & 7, n1g = tid >> 3;
#pragma unroll
        for (int i = 0; i < 4; i++) {
            int n1 = n1g + 64 * i;
            int g  = n1 * N2 + n2base + 2 * cp;
            float2 a = *(const float2*)(rp + g);
            float2 b = ip ? *(const float2*)(ip + g) : make_float2(0.f, 0.f);
            s[n1 * 16 + 2 * cp]     = make_float2(a.x, b.x);
            s[n1 * 16 + 2 * cp + 1] = make_float2(a.y, b.y);
        }
    }
    __syncthreads();

    const int c = tid & 15, r = tid >> 4;         // r in [0,32)

    // fused (256,128): chained twiddle, step = W_512^{32} = e^{-i pi/8}
    {
        float2 w1 = expif((float)r * (-PI_F / 256.f));
        const float2 stp = make_float2(0.92387953251f, -0.38268343236f);
#pragma unroll
        for (int qq = 0; qq < 4; qq++) {
            int j = r + 32 * qq;
            float2 w2 = csq(w1);
            float2 a0 = s[j * 16 + c], a1 = s[(j + 128) * 16 + c];
            float2 b2 = cmul(w1, a0);
            float2 t  = cmul(w1, a1);
            float2 b3 = make_float2(t.y, -t.x);
            s[j * 16 + c]         = cadd(a0, a1);
            s[(j + 128) * 16 + c] = cmul(w2, csub(a0, a1));
            s[(j + 256) * 16 + c] = cadd(b2, b3);
            s[(j + 384) * 16 + c] = cmul(w2, csub(b2, b3));
            w1 = cmul(w1, stp);
        }
    }
    __syncthreads();

    // fused (64,32): j = r invariant across qq
    {
        float2 w1 = expif((float)r * (-PI_F / 64.f));
        float2 w2 = csq(w1);
#pragma unroll
        for (int qq = 0; qq < 4; qq++) {
            int p0 = qq * 128 + r;
            float2 a0 = s[p0*16+c], a1 = s[(p0+32)*16+c], a2 = s[(p0+64)*16+c], a3 = s[(p0+96)*16+c];
            dif4(a0, a1, a2, a3, w1, w2);
            s[p0*16+c] = a0; s[(p0+32)*16+c] = a1; s[(p0+64)*16+c] = a2; s[(p0+96)*16+c] = a3;
        }
    }
    __syncthreads();

    // fused (16,8): j = r&7 invariant across qq
    {
        float2 w1 = expif((float)(r & 7) * (-PI_F / 16.f));
        float2 w2 = csq(w1);
#pragma unroll
        for (int qq = 0; qq < 4; qq++) {
            int g = (r >> 3) + 4 * qq;
            int p0 = g * 32 + (r & 7);
            float2 a0 = s[p0*16+c], a1 = s[(p0+8)*16+c], a2 = s[(p0+16)*16+c], a3 = s[(p0+24)*16+c];
            dif4(a0, a1, a2, a3, w1, w2);
            s[p0*16+c] = a0; s[(p0+8)*16+c] = a1; s[(p0+16)*16+c] = a2; s[(p0+24)*16+c] = a3;
        }
    }
    __syncthreads();

    // register octets: fused (4,2) + h=1, big twiddle via power chain, store
    const int n2 = n2base + c;
    const float2 w1c = make_float2(R2_F, -R2_F);  // W_8^1
    const float2 w2c = make_float2(0.f, -1.f);    // W_4^1
    const float2 one = make_float2(1.f, 0.f);
    const float2 w64 = expif((float)n2 * (-PI_F / 1024.f));   // W_N^{64*n2}
#pragma unroll
    for (int o = 0; o < 2; o++) {
        int base = 8 * (r + 32 * o);
        float2 v[8];
#pragma unroll
        for (int m = 0; m < 8; m++) v[m] = s[(base + m) * 16 + c];
        dif4(v[0], v[2], v[4], v[6], one, one);
        dif4(v[1], v[3], v[5], v[7], w1c, w2c);
#pragma unroll
        for (int m = 0; m < 8; m += 2) {
            float2 a = v[m], b = v[m + 1];
            v[m] = cadd(a, b); v[m + 1] = csub(a, b);
        }
        const int Kb = brev9(base);               // < 64
        float2 wK = expif((float)(n2 * Kb) * (-2.f * PI_F / (float)N_FFT));
        float2 pw[8];
        pw[0] = one;
#pragma unroll
        for (int k = 1; k < 8; k++) pw[k] = cmul(pw[k-1], w64);
        const int b3tab[8] = {0,4,2,6,1,5,3,7};
#pragma unroll
        for (int m = 0; m < 8; m++) {
            int b  = b3tab[m];
            int k1 = Kb + 64 * b;
            float2 w = cmul(wK, pw[b]);
            float2 rv = cmul(v[m], w);
            if (HALF) {
                h2* drow = (h2*)dstv + (size_t)row * N_FFT;
                drow[(size_t)k1 * N2 + n2] = f2h(rv);
            } else {
                float2* drow = (float2*)dstv + (size_t)row * N_FFT;
                drow[(size_t)k1 * N2 + n2] = rv;
            }
        }
    }
}

// ---------------------------------------------------------------------------
// Row-kernel LDS pitch: 18 float2 per 16-point group => b64/b128 accesses at
// the bank-conflict minimum, 16B-aligned row bases for float4 packing.
// ---------------------------------------------------------------------------
#define RPITCH 18

// ---------------------------------------------------------------------------
// Filter row FFTs: 256-pt forward via 16x16 four-step, FFT-16 in registers.
// Output layout matches mid_rows' register permutation:
//   Ghat[row*256 + 16*t + p] = X[t + 16*BR[p]]   (t = thread-in-row)
// In-place on G (safe: stores depend on all row loads through the LDS
// exchange; wave-wide vmcnt drains before ds_write; DS is per-wave in-order).
// ---------------------------------------------------------------------------
__global__ __launch_bounds__(128) void fwd_rows_g(float2* __restrict__ G)
{
    __shared__ __align__(16) float2 s[8 * 16 * RPITCH + 16 * RPITCH];
    const int tid = threadIdx.x;
    const int t = tid & 15, rl = tid >> 4;
    const long long row = (long long)blockIdx.x * 8 + rl;
    float2* tab = s + 8 * 16 * RPITCH;

    { // W256^{b*c} table, pitch 18; 128 threads cover 256 entries
        int b0 = tid >> 4, c0 = tid & 15;
        tab[b0 * RPITCH + c0] = expif((float)(b0 * c0) * (-2.f * PI_F / 256.f));
        int e = tid + 128, b1 = e >> 4, c1 = e & 15;
        tab[b1 * RPITCH + c1] = expif((float)(b1 * c1) * (-2.f * PI_F / 256.f));
    }
    __syncthreads();

    // strided load: thread t holds x[16a + t], a = 0..15
    const float2* gp = G + (size_t)row * N2 + t;
    float2 v[16];
#pragma unroll
    for (int a = 0; a < 16; a++) v[a] = gp[16 * a];

    fft16_fwd(v);                                 // over a -> c = BR[p]
#pragma unroll
    for (int p = 1; p < 16; p++) v[p] = cmul(v[p], tab[t * RPITCH + BR[p]]);

    // exchange: write [b=t][c], read [b][c'=t]  (intra-wave)
    float2* rS = s + rl * (16 * RPITCH);
    float4* rS4 = (float4*)rS;
#pragma unroll
    for (int k = 0; k < 8; k++) {
        float2 e = v[BR[2*k]], o = v[BR[2*k] + 8];    // c = 2k, 2k+1
        rS4[(t * RPITCH + 2*k) >> 1] = make_float4(e.x, e.y, o.x, o.y);
    }
    asm volatile("s_waitcnt lgkmcnt(0)" ::: "memory");
#pragma unroll
    for (int b = 0; b < 16; b++) v[b] = rS[b * RPITCH + t];

    fft16_fwd(v);                                 // over b -> X[t + 16*BR[p]]

    float4* o4 = (float4*)(G + (size_t)row * N2 + 16 * t);
#pragma unroll
    for (int m = 0; m < 8; m++)
        o4[m] = make_float4(v[2*m].x, v[2*m].y, v[2*m+1].x, v[2*m+1].y);
}

// ---------------------------------------------------------------------------
// Fused mid: fwd row FFT -> x Ghat -> inv row FFT -> conj big twiddle.
// 16x16 four-step, FFT-16 in registers; 16 rows/block, 16 threads/row
// (each row lives in one wave -> exchanges need no __syncthreads).
// fp16 global, fp32 compute. One barrier total (table init).
// ---------------------------------------------------------------------------
__global__ __launch_bounds__(256, 4) void mid_rows(
    h2* __restrict__ buf, const float2* __restrict__ Gh)
{
    __shared__ __align__(16) float2 s[16 * 16 * RPITCH + 16 * RPITCH];
    const int tid = threadIdx.x;
    const int t = tid & 15, rl = tid >> 4;
    const long long row = (long long)blockIdx.x * 16 + rl;
    const int k1 = (int)(row & (N1 - 1));
    float2* tab = s + 16 * 16 * RPITCH;

    { // W256^{b*c} table, one entry per thread
        int b = tid >> 4, c = tid & 15;
        tab[b * RPITCH + c] = expif((float)(b * c) * (-2.f * PI_F / 256.f));
    }
    __syncthreads();                              // the only barrier

    // strided load: thread t holds row[16a + t] (fp16 complex), a = 0..15
    h2* bp = buf + ((size_t)row * N2 + t);
    float2 v[16];
#pragma unroll
    for (int a = 0; a < 16; a++) {
        h2 h = bp[16 * a];
        v[a] = make_float2((float)h.x, (float)h.y);
    }

    // ---- forward: FFT-16 over a, twiddle W256^{t*c}, exchange, FFT-16 over b
    fft16_fwd(v);
#pragma unroll
    for (int p = 1; p < 16; p++) v[p] = cmul(v[p], tab[t * RPITCH + BR[p]]);

    float2* rS = s + rl * (16 * RPITCH);
    float4* rS4 = (float4*)rS;
#pragma unroll
    for (int k = 0; k < 8; k++) {
        float2 e = v[BR[2*k]], o = v[BR[2*k] + 8];
        rS4[(t * RPITCH + 2*k) >> 1] = make_float4(e.x, e.y, o.x, o.y);
    }

    // prefetch Ghat row while the exchange + 2nd FFT run (used at pointwise)
    const float4* g4 = (const float4*)(Gh + ((size_t)k1 * N2 + 16 * t));
    float4 g[8];
#pragma unroll
    for (int m = 0; m < 8; m++) g[m] = g4[m];

    asm volatile("s_waitcnt lgkmcnt(0)" ::: "memory");
#pragma unroll
    for (int b = 0; b < 16; b++) v[b] = rS[b * RPITCH + t];

    fft16_fwd(v);                                 // reg p <-> X[t + 16*BR[p]]

    // ---- pointwise with Ghat (same permutation on both sides)
#pragma unroll
    for (int m = 0; m < 8; m++) {
        v[2*m]   = cmul(v[2*m],   make_float2(g[m].x, g[m].y));
        v[2*m+1] = cmul(v[2*m+1], make_float2(g[m].z, g[m].w));
    }

    // ---- inverse: FFT-16 over d (brev-in), conj twiddle, exchange, FFT-16 over c
    fft16_inv(v);                                 // v[b] natural b
#pragma unroll
    for (int b = 1; b < 16; b++) v[b] = cmulc(v[b], tab[b * RPITCH + t]);

#pragma unroll
    for (int m = 0; m < 8; m++)
        rS4[(t * RPITCH + 2*m) >> 1] = make_float4(v[2*m].x, v[2*m].y, v[2*m+1].x, v[2*m+1].y);
    asm volatile("s_waitcnt lgkmcnt(0)" ::: "memory");
#pragma unroll
    for (int c = 0; c < 16; c++) v[BR[c]] = rS[c * RPITCH + t];   // brev-in

    fft16_inv(v);                                 // v[a] = z[16a + t], natural

    // ---- conj big twiddle W_N^{+n2*k1}, n2 = 16a + t, chained; h2 stores
    {
        const float th = 2.f * PI_F / (float)N_FFT;
        float2 w = expif((float)(k1 * t) * th);
        const float2 stp = expif((float)(16 * k1) * th);
#pragma unroll
        for (int a = 0; a < 16; a++) {
            float2 r = cmul(v[a], w);
            bp[16 * a] = f2h(r);
            if (a < 15) w = cmul(w, stp);
        }
    }
}

// ---------------------------------------------------------------------------
// Inverse column FFT (512-pt DIT, brev load) over k1, scale, keep n1<256.
// ---------------------------------------------------------------------------
__global__ __launch_bounds__(512, 4) void inv_cols(
    const h2* __restrict__ src, float* __restrict__ out)
{
    __shared__ float4 s4[N1 * 16 / 2];            // 64 KB
    float2* s = (float2*)s4;
    const int tile = blockIdx.x, row = blockIdx.y, tid = threadIdx.x;
    const int n2base = tile * 16;
    const h2* srow = src + (size_t)row * N_FFT;
    const int cp = tid & 7, r8 = tid >> 3;        // r8 in [0,64)

#pragma unroll
    for (int i = 0; i < 8; i++) {
        int k1 = r8 + 64 * i;
        h4 v = *((const h4*)(srow + (size_t)k1 * N2 + n2base + 2 * cp));
        int p = brev9(k1);
        s4[p * 8 + cp] = make_float4((float)v.x, (float)v.y, (float)v.z, (float)v.w);
    }
    __syncthreads();

    const int c = tid & 15, r = tid >> 4;         // r in [0,32)

    // register octets: h=1 then fused (2,4), inverse constants
    const float2 w1c = make_float2(0.f, 1.f);     // conj(W_4^1) = i
    const float2 w2c = make_float2(R2_F, R2_F);   // conj(W_8^1)
    const float2 one = make_float2(1.f, 0.f);
#pragma unroll
    for (int o = 0; o < 2; o++) {
        int base = 8 * (r + 32 * o);
        float2 v[8];
#pragma unroll
        for (int m = 0; m < 8; m++) v[m] = s[(base + m) * 16 + c];
#pragma unroll
        for (int m = 0; m < 8; m += 2) {
            float2 a = v[m], b = v[m + 1];
            v[m] = cadd(a, b); v[m + 1] = csub(a, b);
        }
        dit4i(v[0], v[2], v[4], v[6], one, one);
        dit4i(v[1], v[3], v[5], v[7], w1c, w2c);
#pragma unroll
        for (int m = 0; m < 8; m++) s[(base + m) * 16 + c] = v[m];
    }
    __syncthreads();

    // fused (8,16): j = r&7 invariant
    {
        float2 w2 = expif((float)(r & 7) * (PI_F / 16.f));
        float2 w1 = csq(w2);
#pragma unroll
        for (int qq = 0; qq < 4; qq++) {
            int g = (r >> 3) + 4 * qq;
            int p0 = g * 32 + (r & 7);
            float2 a0 = s[p0*16+c], a1 = s[(p0+8)*16+c], a2 = s[(p0+16)*16+c], a3 = s[(p0+24)*16+c];
            dit4i(a0, a1, a2, a3, w1, w2);
            s[p0*16+c] = a0; s[(p0+8)*16+c] = a1; s[(p0+16)*16+c] = a2; s[(p0+24)*16+c] = a3;
        }
    }
    __syncthreads();
    // fused (32,64): j = r invariant
    {
        float2 w2 = expif((float)r * (PI_F / 64.f));
        float2 w1 = csq(w2);
#pragma unroll
        for (int qq = 0; qq < 4; qq++) {
            int p0 = qq * 128 + r;
            float2 a0 = s[p0*16+c], a1 = s[(p0+32)*16+c], a2 = s[(p0+64)*16+c], a3 = s[(p0+96)*16+c];
            dit4i(a0, a1, a2, a3, w1, w2);
            s[p0*16+c] = a0; s[(p0+32)*16+c] = a1; s[(p0+64)*16+c] = a2; s[(p0+96)*16+c] = a3;
        }
    }
    __syncthreads();
    // fused (128,256): chained, step = e^{+i pi/8}
    {
        float2 w2 = expif((float)r * (PI_F / 256.f));
        const float2 stp = make_float2(0.92387953251f, 0.38268343236f);
#pragma unroll
        for (int qq = 0; qq < 4; qq++) {
            int j = r + 32 * qq;
            float2 w1 = csq(w2);
            float2 a0 = s[j*16+c], a1 = s[(j+128)*16+c], a2 = s[(j+256)*16+c], a3 = s[(j+384)*16+c];
            dit4i(a0, a1, a2, a3, w1, w2);
            s[j*16+c] = a0; s[(j+128)*16+c] = a1; s[(j+256)*16+c] = a2; s[(j+384)*16+c] = a3;
            w2 = cmul(w2, stp);
        }
    }
    __syncthreads();

    const float scale = 1.0f / (float)N_FFT;
    float* out0 = out + (size_t)(2 * row) * T_LEN;
    float* out1 = out + (size_t)(2 * row + 1) * T_LEN;
#pragma unroll
    for (int i = 0; i < 4; i++) {
        int p = r8 + 64 * i;                      // p < 256
        float4 q = s4[p * 8 + cp];
        int n = p * N2 + n2base + 2 * cp;
        *(float2*)(out0 + n) = make_float2(q.x * scale, q.z * scale);
        *(float2*)(out1 + n) = make_float2(q.y * scale, q.w * scale);
    }
}

extern "C" void kernel_launch(void* const* d_in, const int* in_sizes, int n_in,
                              void* d_out, int out_size, void* d_ws, size_t ws_size,
                              hipStream_t stream) {
    const float* x    = (const float*)d_in[0];
    const float* filt = (const float*)d_in[1];
    float* out = (float*)d_out;

    h2* buf = (h2*)d_ws;                                                        // 67 MB
    float2* G = (float2*)((char*)d_ws + (size_t)CB * N_FFT * sizeof(h2));       // 1 MB

    fwd_cols<false><<<dim3(16, 1), 512, 0, stream>>>(filt, nullptr, 0LL, (void*)G);
    fwd_rows_g<<<N1 / 8, 128, 0, stream>>>(G);
    fwd_cols<true><<<dim3(16, CB), 512, 0, stream>>>(x, x + T_LEN, (long long)(2 * T_LEN), (void*)buf);
    mid_rows<<<(CB * N1) / 16, 256, 0, stream>>>(buf, G);
    inv_cols<<<dim3(16, CB), 512, 0, stream>>>(buf, out);
}